// Round 4
// baseline (66.809 us; speedup 1.0000x reference)
//
#include <hip/hip_runtime.h>
#include <math.h>

#define HIDDEN 1000
#define K4 250   // HIDDEN / 4 float4s per row

__device__ __forceinline__ float sigmoidf_(float x) {
  return 1.f / (1.f + expf(-x));
}

// Block-wide (256 thr) 3-row matvec partial: thread t<250 loads h float4 and
// 3 weight float4s (independent), reduces via shuffle+LDS. Results in r0,r1,r2
// valid on thread 0 only.
__device__ __forceinline__ void block_dot3(const float4* __restrict__ row0,
                                           const float4* __restrict__ row1,
                                           const float4* __restrict__ row2,
                                           const float4* __restrict__ hv4,
                                           int t, float& r0, float& r1, float& r2) {
  float a0 = 0.f, a1 = 0.f, a2 = 0.f;
  if (t < K4) {
    float4 hv = hv4[t];
    float4 w0 = row0[t];
    float4 w1 = row1[t];
    float4 w2 = row2[t];
    a0 = fmaf(w0.x, hv.x, fmaf(w0.y, hv.y, fmaf(w0.z, hv.z, w0.w * hv.w)));
    a1 = fmaf(w1.x, hv.x, fmaf(w1.y, hv.y, fmaf(w1.z, hv.z, w1.w * hv.w)));
    a2 = fmaf(w2.x, hv.x, fmaf(w2.y, hv.y, fmaf(w2.z, hv.z, w2.w * hv.w)));
  }
  #pragma unroll
  for (int off = 32; off; off >>= 1) {
    a0 += __shfl_xor(a0, off);
    a1 += __shfl_xor(a1, off);
    a2 += __shfl_xor(a2, off);
  }
  __shared__ float s[4][3];
  const int wave = t >> 6, lane = t & 63;
  if (lane == 0) { s[wave][0] = a0; s[wave][1] = a1; s[wave][2] = a2; }
  __syncthreads();
  if (t == 0) {
    r0 = s[0][0] + s[1][0] + s[2][0] + s[3][0];
    r1 = s[0][1] + s[1][1] + s[2][1] + s[3][1];
    r2 = s[0][2] + s[1][2] + s[2][2] + s[3][2];
  }
}

// Phase A: block (l,j) per (layer,neuron), 8000 blocks.
//   l==0: 3 gh dots + tiny gi + gate -> h0, out. Block 0 also inits out[0]=b_out.
//   l>=1: 3 gh dots + bhh -> gh_ws.
__global__ __launch_bounds__(256)
void gru_phaseA(const float* __restrict__ x,        // [2]
                const float* __restrict__ hiddens,  // [8*1000]
                const float* __restrict__ Wih0,     // [3000*2]
                const float* __restrict__ Whh,      // [8*3000*1000]
                const float* __restrict__ bih,      // [8*3000]
                const float* __restrict__ bhh,      // [8*3000]
                const float* __restrict__ bout,     // [1]
                float* __restrict__ gh_ws,          // [7*3000]
                float* __restrict__ h_buf,          // [8*1000]
                float* __restrict__ out)            // [8001]
{
  const int t = threadIdx.x;
  const int b = blockIdx.x;
  const int l = b / 1000;        // 0..7
  const int j = b - l * 1000;    // 0..999

  const float4* W4 = reinterpret_cast<const float4*>(
      Whh + (size_t)l * 3000 * HIDDEN);
  const float4* hv4 = reinterpret_cast<const float4*>(
      hiddens + (size_t)l * HIDDEN);

  float ghr, ghz, ghn;
  block_dot3(W4 + (size_t)(j)        * K4,
             W4 + (size_t)(1000 + j) * K4,
             W4 + (size_t)(2000 + j) * K4,
             hv4, t, ghr, ghz, ghn);

  if (t == 0) {
    if (l == 0) {
      const float x0 = x[0], x1 = x[1];
      float gir = Wih0[2*j]        * x0 + Wih0[2*j+1]        * x1 + bih[j];
      float giz = Wih0[2*(1000+j)] * x0 + Wih0[2*(1000+j)+1] * x1 + bih[1000 + j];
      float gin = Wih0[2*(2000+j)] * x0 + Wih0[2*(2000+j)+1] * x1 + bih[2000 + j];
      float r = sigmoidf_(gir + ghr + bhh[j]);
      float z = sigmoidf_(giz + ghz + bhh[1000 + j]);
      float n = tanhf(gin + r * (ghn + bhh[2000 + j]));
      float h = (1.f - z) * n + z * hiddens[j];
      h_buf[j] = h;
      out[1 + j] = h;
      if (j == 0) out[0] = bout[0];   // init for layer-7 atomic flow
    } else {
      gh_ws[(l-1)*3000 + j]        = ghr + bhh[l*3000 + j];
      gh_ws[(l-1)*3000 + 1000 + j] = ghz + bhh[l*3000 + 1000 + j];
      gh_ws[(l-1)*3000 + 2000 + j] = ghn + bhh[l*3000 + 2000 + j];
    }
  }
}

// One layer (l in 1..7): block per neuron; gi matvec + gate. Layer 7 also
// accumulates flow: out[0] += Wout[j] * h7[j] (out[0] pre-set to b_out).
__global__ __launch_bounds__(256)
void gru_layer2(const int l,
                const float* __restrict__ hiddens,  // [8*1000]
                const float* __restrict__ Wih,      // [7*3000*1000]
                const float* __restrict__ bih,      // [8*3000]
                const float* __restrict__ gh_ws,    // [7*3000] (bhh included)
                const float* __restrict__ Wout,     // [1000]
                float* __restrict__ h_buf,          // [8*1000]
                float* __restrict__ out)            // [8001]
{
  const int t = threadIdx.x;
  const int j = blockIdx.x;                // neuron 0..999
  const float4* W4  = reinterpret_cast<const float4*>(
      Wih + (size_t)(l - 1) * 3000 * HIDDEN);
  const float4* hin = reinterpret_cast<const float4*>(
      h_buf + (size_t)(l - 1) * HIDDEN);

  float gir, giz, gin;
  block_dot3(W4 + (size_t)(j)        * K4,
             W4 + (size_t)(1000 + j) * K4,
             W4 + (size_t)(2000 + j) * K4,
             hin, t, gir, giz, gin);

  if (t == 0) {
    float ghr = gh_ws[(l-1)*3000 + j];
    float ghz = gh_ws[(l-1)*3000 + 1000 + j];
    float ghn = gh_ws[(l-1)*3000 + 2000 + j];
    float r = sigmoidf_(gir + bih[l*3000 + j] + ghr);
    float z = sigmoidf_(giz + bih[l*3000 + 1000 + j] + ghz);
    float n = tanhf(gin + bih[l*3000 + 2000 + j] + r * ghn);
    float h = (1.f - z) * n + z * hiddens[(size_t)l * HIDDEN + j];
    h_buf[l * HIDDEN + j] = h;
    out[1 + l * HIDDEN + j] = h;
    if (l == 7) atomicAdd(&out[0], Wout[j] * h);
  }
}

extern "C" void kernel_launch(void* const* d_in, const int* in_sizes, int n_in,
                              void* d_out, int out_size, void* d_ws, size_t ws_size,
                              hipStream_t stream) {
  const float* x       = (const float*)d_in[0];
  const float* hiddens = (const float*)d_in[1];
  const float* Wih0    = (const float*)d_in[2];
  const float* Wih     = (const float*)d_in[3];
  const float* Whh     = (const float*)d_in[4];
  const float* bih     = (const float*)d_in[5];
  const float* bhh     = (const float*)d_in[6];
  const float* Wout    = (const float*)d_in[7];
  const float* bout    = (const float*)d_in[8];
  float* out   = (float*)d_out;
  float* gh_ws = (float*)d_ws;          // 21000 floats (layers 1..7 gh)
  float* h_buf = gh_ws + 21000;         // 8000 floats

  gru_phaseA<<<8000, 256, 0, stream>>>(x, hiddens, Wih0, Whh, bih, bhh, bout,
                                       gh_ws, h_buf, out);
  for (int l = 1; l < 8; ++l) {
    gru_layer2<<<1000, 256, 0, stream>>>(l, hiddens, Wih, bih, gh_ws, Wout,
                                         h_buf, out);
  }
}